// Round 2
// baseline (447.368 us; speedup 1.0000x reference)
//
#include <hip/hip_runtime.h>
#include <hip/hip_bf16.h>
#include <stdint.h>
#include <math.h>

// ===== Problem constants =====
#define BB 8
#define LL 4096
#define HH 4
#define DD 8      // IN_DIM
#define VV 4      // FFN_V
#define DEPTH 8   // FFN_DEPTH
#define TBLN 256
#define NBIT 8
#define NROW 131072   // B*L*H
#define CHUNK 64
#define NCHUNK 64     // L / CHUNK

// JAX threefry mode: 1 = partitionable (default since jax 0.4.36), 0 = legacy split-iota
#define PARTITIONABLE 1
// Math provenance: 1 = XLA-CPU Cephes-style vectorized exp/log (no FMA), 0 = device OCML
#define MATH_XLA_CPU 1

__device__ __forceinline__ uint32_t rotl32(uint32_t v, int r){ return (v<<r)|(v>>(32-r)); }

__device__ __forceinline__ void tf2x32(uint32_t k0, uint32_t k1, uint32_t x0, uint32_t x1,
                                       uint32_t& o0, uint32_t& o1){
  uint32_t ks2 = k0 ^ k1 ^ 0x1BD11BDAu;
  x0 += k0; x1 += k1;
  x0+=x1; x1=rotl32(x1,13); x1^=x0;
  x0+=x1; x1=rotl32(x1,15); x1^=x0;
  x0+=x1; x1=rotl32(x1,26); x1^=x0;
  x0+=x1; x1=rotl32(x1, 6); x1^=x0;
  x0+=k1; x1+=ks2+1u;
  x0+=x1; x1=rotl32(x1,17); x1^=x0;
  x0+=x1; x1=rotl32(x1,29); x1^=x0;
  x0+=x1; x1=rotl32(x1,16); x1^=x0;
  x0+=x1; x1=rotl32(x1,24); x1^=x0;
  x0+=ks2; x1+=k0+2u;
  x0+=x1; x1=rotl32(x1,13); x1^=x0;
  x0+=x1; x1=rotl32(x1,15); x1^=x0;
  x0+=x1; x1=rotl32(x1,26); x1^=x0;
  x0+=x1; x1=rotl32(x1, 6); x1^=x0;
  x0+=k0; x1+=k1+3u;
  x0+=x1; x1=rotl32(x1,17); x1^=x0;
  x0+=x1; x1=rotl32(x1,29); x1^=x0;
  x0+=x1; x1=rotl32(x1,16); x1^=x0;
  x0+=x1; x1=rotl32(x1,24); x1^=x0;
  x0+=k1; x1+=ks2+4u;
  x0+=x1; x1=rotl32(x1,13); x1^=x0;
  x0+=x1; x1=rotl32(x1,15); x1^=x0;
  x0+=x1; x1=rotl32(x1,26); x1^=x0;
  x0+=x1; x1=rotl32(x1, 6); x1^=x0;
  x0+=ks2; x1+=k0+5u;
  o0 = x0; o1 = x1;
}

struct K2 { uint32_t a, b; };
__device__ __forceinline__ K2 kfold(K2 k, uint32_t d){
  K2 r; tf2x32(k.a, k.b, 0u, d, r.a, r.b); return r;
}

__device__ __forceinline__ uint32_t rbits(K2 k, uint32_t p, uint32_t n){
#if PARTITIONABLE
  uint32_t o0, o1; tf2x32(k.a, k.b, 0u, p, o0, o1); return o0 ^ o1;
#else
  uint32_t half = n >> 1;  // n is even in every use here
  uint32_t o0, o1;
  if (p < half){ tf2x32(k.a, k.b, p, p + half, o0, o1); return o0; }
  else         { tf2x32(k.a, k.b, p - half, p, o0, o1); return o1; }
#endif
}

__device__ __forceinline__ float bits2u(uint32_t b){
  return __uint_as_float((b >> 9) | 0x3f800000u) - 1.0f;
}

// ===== Bit-exact XLA-CPU style math (Cephes/Eigen structure, strict f32, no FMA) =====
__device__ __forceinline__ float xla_expf(float x){
#if MATH_XLA_CPU
  #pragma clang fp contract(off)
  const float exp_hi = 88.3762626647950f;
  const float exp_lo = -88.3762626647949f;
  const float log2e  = 1.44269504088896341f;
  const float c1 = 0.693359375f;
  const float c2 = -2.12194440e-4f;
  float xc = fmaxf(fminf(x, exp_hi), exp_lo);
  float fx = floorf(xc * log2e + 0.5f);
  float tmp = fx * c1;
  float z1  = fx * c2;
  float r = xc - tmp;
  r = r - z1;
  float z = r * r;
  float y = 1.9875691500E-4f;
  y = y * r + 1.3981999507E-3f;
  y = y * r + 8.3334519073E-3f;
  y = y * r + 4.1665795894E-2f;
  y = y * r + 1.6666665459E-1f;
  y = y * r + 5.0000001201E-1f;
  y = y * z + r;
  y = y + 1.0f;
  int emm0 = (int)fx + 127;
  float scale = __int_as_float(emm0 << 23);
  return fmaxf(y * scale, x);
#else
  return expf(x);
#endif
}

__device__ __forceinline__ float xla_logf(float a){
#if MATH_XLA_CPU
  #pragma clang fp contract(off)
  float x = fmaxf(a, __uint_as_float(0x00800000u));  // flush denormals
  uint32_t bits = __float_as_uint(x);
  int em = (int)(bits >> 23) - 126;
  x = __uint_as_float((bits & 0x007fffffu) | 0x3f000000u);  // mantissa in [0.5,1)
  float e = (float)em;
  bool mlt = x < 0.707106781186547524f;
  float tmp1 = mlt ? x : 0.0f;
  float xm = x - 1.0f;
  e = e - (mlt ? 1.0f : 0.0f);
  xm = xm + tmp1;
  float z = xm * xm;
  float y = 7.0376836292E-2f;
  y = y * xm + (-1.1514610310E-1f);
  y = y * xm + 1.1676998740E-1f;
  y = y * xm + (-1.2420140846E-1f);
  y = y * xm + 1.4249322787E-1f;
  y = y * xm + (-1.6668057665E-1f);
  y = y * xm + 2.0000714765E-1f;
  y = y * xm + (-2.4999993993E-1f);
  y = y * xm + 3.3333331174E-1f;
  y = y * xm;
  y = y * z;
  y = e * (-2.12194440e-4f) + y;
  y = y - 0.5f * z;
  float res = xm + y;
  res = e * 0.693359375f + res;
  return res;   // inputs here are always positive/normal
#else
  return logf(a);
#endif
}

__device__ __forceinline__ float xla_log1pf(float x){
#if MATH_XLA_CPU
  #pragma clang fp contract(off)
  if (fabsf(x) < 1e-4f){
    return ((-0.5f * x) + 1.0f) * x;
  }
  return xla_logf(1.0f + x);
#else
  return log1pf(x);
#endif
}

// jnp.logaddexp: amax + log1p(exp(-|a-b|))  (no NaNs in this workload)
__device__ __forceinline__ float xla_logaddexp(float a, float b){
  #pragma clang fp contract(off)
  float m = fmaxf(a, b);
  float d = a - b;
  return m + xla_log1pf(xla_expf(-fabsf(d)));
}

// -logsumexp(-v): amax = max(-v); log(sum exp(-v - amax)) + amax; negate.
template<int NV>
__device__ __forceinline__ float neg_lse_neg(const float* v){
  #pragma clang fp contract(off)
  float m = -v[0];
  #pragma unroll
  for (int i = 1; i < NV; i++) m = fmaxf(m, -v[i]);
  float s = 0.f;
  #pragma unroll
  for (int i = 0; i < NV; i++) s = s + xla_expf((-v[i]) - m);
  return -(xla_logf(s) + m);
}

// bernoulli: u < sigmoid(w); sigmoid = 1/(1+exp(-w)) per XLA LogisticExpander
__device__ __forceinline__ bool bern_bit(float u, float w){
  #pragma clang fp contract(off)
  float e = xla_expf(-w);
  float s = 1.0f / (1.0f + e);
  return u < s;
}

// fast soft-AND for analog-only paths: -logaddexp(-a,-b). andf(+inf,b)==b.
__device__ __forceinline__ float andf(float a, float b){
  float na = -a, nb = -b;
  float m = fmaxf(na, nb);
  float d = fabsf(na - nb);
  return -(m + log1pf(expf(-d)));
}

// ===== Kernel 0: detect bool-input layout (u8 vs 4-byte int/float) =====
__global__ void k_detect(const uint32_t* xw, int* flag){
  __shared__ int any;
  if (threadIdx.x == 0) any = 0;
  __syncthreads();
  int bad = 0;
  for (int i = threadIdx.x; i < 1024; i += 256){
    uint32_t w = xw[i];
    if (w != 0u && w != 1u && w != 0x3F800000u) bad = 1;
  }
  if (bad) atomicOr(&any, 1);
  __syncthreads();
  if (threadIdx.x == 0) *flag = any;   // 1 -> u8 layout, 0 -> 4-byte layout
}

// ===== Kernel 1: tree-FFN -> xcode (4-bit) + xss per (b,l,h) row =====
__global__ __launch_bounds__(256) void k_ffn(const void* xraw, const float* xs,
                                             const float* fk, const float* fv,
                                             uint8_t* xcode, float* xss, const int* flag){
  int r = blockIdx.x * blockDim.x + threadIdx.x;
  if (r >= NROW) return;
  int n = r >> 2;
  int h = r & 3;
  bool u8mode = (*flag != 0);
  const uint8_t* x8   = (const uint8_t*)xraw;
  const uint32_t* x32 = (const uint32_t*)xraw;

  float qs[DD];
  #pragma unroll
  for (int j = 0; j < DD; j++){
    bool qb = u8mode ? (x8[n*DD + j] != 0) : (x32[n*DD + j] != 0u);
    float v = xs[n*DD + j];
    qs[j] = qb ? v : -v;           // (2b-1)*v, exact sign flip
  }

  K2 root{0u, 42u};
  K2 rngT = kfold(root, 1u);

  uint32_t ix = 0;
  float support = 0.f;
  for (int d = 0; d < DEPTH; d++){
    K2 kd = kfold(rngT, (uint32_t)d);
    const float* kw = fk + (size_t)(h*255 + (1<<d) - 1 + (int)ix) * 16;
    float lor[DD];
    #pragma unroll
    for (int j = 0; j < DD; j++){
      uint32_t p1 = (uint32_t)r * 16u + 2u*(uint32_t)j;
      float u1 = bits2u(rbits(kd, p1,      2097152u));
      float u2 = bits2u(rbits(kd, p1 + 1u, 2097152u));
      float b1 = bern_bit(u1, kw[2*j])     ? 1.f : 0.f;
      float b2 = bern_bit(u2, kw[2*j + 1]) ? 1.f : 0.f;
      float k1 = -xla_logaddexp(-b1,  qs[j]);
      float k2 = -xla_logaddexp(-b2, -qs[j]);
      lor[j] = xla_logaddexp(k1, k2);
    }
    float lor_s = neg_lse_neg<DD>(lor);
    K2 lk = kfold(rngT, 100u + (uint32_t)d);
    float ul = bits2u(rbits(lk, (uint32_t)r, 131072u));
    bool lb = bern_bit(ul, lor_s);
    float ls = lb ? lor_s : -lor_s;
    ix = 2u*ix + (lb ? 1u : 0u);
    support = (d == 0) ? ls : -xla_logaddexp(-support, -ls);
  }

  K2 vk = kfold(rngT, 999u);
  const float* vw = fv + (size_t)(h*256 + (int)ix) * VV;
  float vs[VV];
  uint32_t code = 0;
  #pragma unroll
  for (int c = 0; c < VV; c++){
    float u = bits2u(rbits(vk, (uint32_t)r*4u + (uint32_t)c, 524288u));
    bool b = bern_bit(u, vw[c]);
    code |= (b ? 1u : 0u) << (VV - 1 - c);
    float sv = b ? vw[c] : -vw[c];
    vs[c] = -xla_logaddexp(-sv, -support);
  }
  xcode[r] = (uint8_t)code;
  xss[r]   = neg_lse_neg<VV>(vs);
}

// ===== Kernel 2: table -> tcode (8-bit next-state) + tabs =====
__global__ __launch_bounds__(256) void k_table(const float* table, uint8_t* tcode, float* tabs){
  int idx = blockIdx.x * blockDim.x + threadIdx.x;   // ((b*64+row)*256 + t)
  if (idx >= 131072) return;
  int rem = idx & 16383;                             // table leading dim is 1 (broadcast over B)
  K2 root{0u, 42u};
  K2 tk = kfold(root, 2u);
  float v[NBIT];
  uint32_t code = 0;
  #pragma unroll
  for (int j = 0; j < NBIT; j++){
    float w = table[(size_t)rem * NBIT + j];
    uint32_t p = (uint32_t)idx * 8u + (uint32_t)j;
    float u = bits2u(rbits(tk, p, 1048576u));
    bool bit = bern_bit(u, w);
    code |= (bit ? 1u : 0u) << (NBIT - 1 - j);
    v[j] = bit ? w : -w;
  }
  tcode[idx] = (uint8_t)code;
  tabs[idx]  = neg_lse_neg<NBIT>(v);
}

// ===== Kernel 3: s0 codes + scores, 32 chains =====
__global__ void k_s0(const float* s0w, int* s0code, float* s0s){
  int t = threadIdx.x;
  if (t >= 32) return;
  int b = t >> 2, h = t & 3;
  K2 root{0u, 42u};
  K2 sk = kfold(root, 3u);
  float v[NBIT];
  uint32_t code = 0;
  #pragma unroll
  for (int j = 0; j < NBIT; j++){
    float w = s0w[h*NBIT + j];
    uint32_t p = (uint32_t)((b*4 + h)*NBIT + j);
    float u = bits2u(rbits(sk, p, 256u));
    bool bit = bern_bit(u, w);
    code |= (bit ? 1u : 0u) << (NBIT - 1 - j);
    v[j] = bit ? w : -w;
  }
  s0code[t] = (int)code;
  s0s[t]    = neg_lse_neg<NBIT>(v);
}

// ===== Kernel 4 (phase A): per-chunk all-state map F + score S =====
__global__ __launch_bounds__(256) void k_phaseA(const uint8_t* tcode, const float* tabs,
                                                const uint8_t* xcode, const float* xss,
                                                uint8_t* F, float* S){
  int blk = blockIdx.x;          // (b*4+h)*64 + c
  int c  = blk & 63;
  int bh = blk >> 6;
  int b = bh >> 2, h = bh & 3;
  __shared__ uint8_t sT[16*256];
  __shared__ float   sS[16*256];
  __shared__ uint8_t sXC[CHUNK];
  __shared__ float   sAX[CHUNK];
  int t = threadIdx.x;
  const int rowbase = (b*64 + h*16) * 256;
  #pragma unroll
  for (int rr = 0; rr < 16; rr++){
    sT[rr*256 + t] = tcode[rowbase + rr*256 + t];
    sS[rr*256 + t] = tabs [rowbase + rr*256 + t];
  }
  if (t < CHUNK){
    int l = c*CHUNK + t;
    int r = (b*LL + l)*HH + h;
    sXC[t] = xcode[r];
    sAX[t] = xss[r];
  }
  __syncthreads();
  for (int off = 32; off > 0; off >>= 1){
    if (t < off) sAX[t] = andf(sAX[t], sAX[t + off]);
    __syncthreads();
  }
  int cur = t;
  float acc = INFINITY;
  for (int k = 0; k < CHUNK; k++){
    int a = (int)sXC[k]*256 + cur;
    acc = andf(acc, sS[a]);
    cur = sT[a];
  }
  F[(size_t)blk*256 + t] = (uint8_t)cur;
  S[(size_t)blk*256 + t] = andf(acc, sAX[0]);
}

// ===== Kernel 5 (phase B): sequential carry across chunks, 32 chains =====
__global__ __launch_bounds__(256) void k_phaseB(const uint8_t* F, const float* S,
                                                const int* s0code, const float* s0s,
                                                int* carryZ, float* carryS){
  int bh = blockIdx.x;           // 0..31
  __shared__ uint8_t sF[NCHUNK*256];
  __shared__ int    zArr[NCHUNK];
  __shared__ float  sv[NCHUNK];
  int t = threadIdx.x;
  for (int k = 0; k < NCHUNK; k++)
    sF[k*256 + t] = F[((size_t)bh*NCHUNK + k)*256 + t];
  __syncthreads();
  if (t == 0){
    int z = s0code[bh];
    for (int c = 0; c < NCHUNK; c++){ zArr[c] = z; z = sF[c*256 + z]; }
  }
  __syncthreads();
  if (t < NCHUNK) sv[t] = S[((size_t)bh*NCHUNK + t)*256 + zArr[t]];
  __syncthreads();
  if (t == 0){
    float zs = s0s[bh];
    for (int c = 0; c < NCHUNK; c++){
      carryZ[bh*NCHUNK + c] = zArr[c];
      carryS[bh*NCHUNK + c] = zs;
      zs = andf(zs, sv[c]);
    }
  }
}

// ===== Kernel 6 (phase C): replay chunk from carry-in, emit outputs (float32) =====
__global__ __launch_bounds__(256) void k_phaseC(const uint8_t* tcode, const float* tabs,
                                                const uint8_t* xcode, const float* xss,
                                                const int* carryZ, const float* carryS,
                                                float* out){
  int blk = blockIdx.x;          // (b*4+h)*64 + c
  int c  = blk & 63;
  int bh = blk >> 6;
  int b = bh >> 2, h = bh & 3;
  __shared__ uint8_t sT[16*256];
  __shared__ float   sS[16*256];
  __shared__ uint8_t sXC[CHUNK];
  __shared__ float   sXS[CHUNK];
  __shared__ int     zOut[CHUNK];
  __shared__ float   sOut[CHUNK];
  int t = threadIdx.x;
  const int rowbase = (b*64 + h*16) * 256;
  #pragma unroll
  for (int rr = 0; rr < 16; rr++){
    sT[rr*256 + t] = tcode[rowbase + rr*256 + t];
    sS[rr*256 + t] = tabs [rowbase + rr*256 + t];
  }
  if (t < CHUNK){
    int l = c*CHUNK + t;
    int r = (b*LL + l)*HH + h;
    sXC[t] = xcode[r];
    sXS[t] = xss[r];
  }
  __syncthreads();
  if (t == 0){
    int z = carryZ[blk];
    float zs = carryS[blk];
    for (int k = 0; k < CHUNK; k++){
      int a = (int)sXC[k]*256 + z;
      zs = andf(zs, andf(sS[a], sXS[k]));
      z = sT[a];
      zOut[k] = z;
      sOut[k] = zs;
    }
  }
  __syncthreads();
  // out0[((b*L+l)*H+h)*8+j] = bit ; out1 at +1048576 floats = zs
  for (int e = t; e < CHUNK*NBIT; e += 256){
    int k = e >> 3, j = e & 7;
    int l = c*CHUNK + k;
    int z = zOut[k];
    int bit = (z >> (NBIT - 1 - j)) & 1;
    size_t o = ((size_t)(b*LL + l)*HH + h)*NBIT + j;
    out[o]           = (float)bit;
    out[1048576 + o] = sOut[k];
  }
}

extern "C" void kernel_launch(void* const* d_in, const int* in_sizes, int n_in,
                              void* d_out, int out_size, void* d_ws, size_t ws_size,
                              hipStream_t stream) {
  const void*  x      = d_in[0];               // bool (layout detected at runtime)
  const float* xs     = (const float*)d_in[1]; // (8,4096,8)
  const float* fk     = (const float*)d_in[2]; // (4,255,16)
  const float* fv     = (const float*)d_in[3]; // (4,256,4)
  const float* table  = (const float*)d_in[4]; // (1,64,256,8)
  const float* s0w    = (const float*)d_in[5]; // (1,4,8)
  float* out          = (float*)d_out;         // [bits 1048576 | scores 1048576]

  uint8_t* ws = (uint8_t*)d_ws;
  uint8_t* xcode_ = ws;                              // 131072 B
  uint8_t* tcode_ = ws + 131072;                     // 131072 B
  uint8_t* F_     = ws + 262144;                     // 524288 B
  float*   xss_   = (float*)(ws + 786432);           // 524288 B
  float*   tabs_  = (float*)(ws + 1310720);          // 524288 B
  float*   S_     = (float*)(ws + 1835008);          // 2097152 B
  int*     carryZ_= (int*)  (ws + 3932160);          // 8192 B
  float*   carryS_= (float*)(ws + 3940352);          // 8192 B
  int*     s0code_= (int*)  (ws + 3948544);          // 128 B
  float*   s0s_   = (float*)(ws + 3948672);          // 128 B
  int*     flag_  = (int*)  (ws + 3948800);          // 4 B

  k_detect<<<1, 256, 0, stream>>>((const uint32_t*)x, flag_);
  k_ffn   <<<NROW/256, 256, 0, stream>>>(x, xs, fk, fv, xcode_, xss_, flag_);
  k_table <<<131072/256, 256, 0, stream>>>(table, tcode_, tabs_);
  k_s0    <<<1, 64, 0, stream>>>(s0w, s0code_, s0s_);
  k_phaseA<<<32*NCHUNK, 256, 0, stream>>>(tcode_, tabs_, xcode_, xss_, F_, S_);
  k_phaseB<<<32, 256, 0, stream>>>(F_, S_, s0code_, s0s_, carryZ_, carryS_);
  k_phaseC<<<32*NCHUNK, 256, 0, stream>>>(tcode_, tabs_, xcode_, xss_, carryZ_, carryS_, out);
}

// Round 3
// 204.730 us; speedup vs baseline: 2.1852x; 2.1852x over previous
//
#include <hip/hip_runtime.h>
#include <hip/hip_bf16.h>
#include <stdint.h>
#include <math.h>

// ===== Problem constants =====
#define BB 8
#define LL 4096
#define HH 4
#define DD 8      // IN_DIM
#define VV 4      // FFN_V
#define DEPTH 8   // FFN_DEPTH
#define TBLN 256
#define NBIT 8
#define NROW 131072   // B*L*H
#define CHUNK 64
#define NCHUNK 64     // L / CHUNK

// JAX threefry mode: 1 = partitionable (default since jax 0.4.36), 0 = legacy split-iota
#define PARTITIONABLE 1
// Math provenance: 1 = XLA-CPU Cephes-style vectorized exp/log (no FMA), 0 = device OCML
#define MATH_XLA_CPU 1

__device__ __forceinline__ uint32_t rotl32(uint32_t v, int r){ return (v<<r)|(v>>(32-r)); }

__device__ __forceinline__ void tf2x32(uint32_t k0, uint32_t k1, uint32_t x0, uint32_t x1,
                                       uint32_t& o0, uint32_t& o1){
  uint32_t ks2 = k0 ^ k1 ^ 0x1BD11BDAu;
  x0 += k0; x1 += k1;
  x0+=x1; x1=rotl32(x1,13); x1^=x0;
  x0+=x1; x1=rotl32(x1,15); x1^=x0;
  x0+=x1; x1=rotl32(x1,26); x1^=x0;
  x0+=x1; x1=rotl32(x1, 6); x1^=x0;
  x0+=k1; x1+=ks2+1u;
  x0+=x1; x1=rotl32(x1,17); x1^=x0;
  x0+=x1; x1=rotl32(x1,29); x1^=x0;
  x0+=x1; x1=rotl32(x1,16); x1^=x0;
  x0+=x1; x1=rotl32(x1,24); x1^=x0;
  x0+=ks2; x1+=k0+2u;
  x0+=x1; x1=rotl32(x1,13); x1^=x0;
  x0+=x1; x1=rotl32(x1,15); x1^=x0;
  x0+=x1; x1=rotl32(x1,26); x1^=x0;
  x0+=x1; x1=rotl32(x1, 6); x1^=x0;
  x0+=k0; x1+=k1+3u;
  x0+=x1; x1=rotl32(x1,17); x1^=x0;
  x0+=x1; x1=rotl32(x1,29); x1^=x0;
  x0+=x1; x1=rotl32(x1,16); x1^=x0;
  x0+=x1; x1=rotl32(x1,24); x1^=x0;
  x0+=k1; x1+=ks2+4u;
  x0+=x1; x1=rotl32(x1,13); x1^=x0;
  x0+=x1; x1=rotl32(x1,15); x1^=x0;
  x0+=x1; x1=rotl32(x1,26); x1^=x0;
  x0+=x1; x1=rotl32(x1, 6); x1^=x0;
  x0+=ks2; x1+=k0+5u;
  o0 = x0; o1 = x1;
}

struct K2 { uint32_t a, b; };
__device__ __forceinline__ K2 kfold(K2 k, uint32_t d){
  K2 r; tf2x32(k.a, k.b, 0u, d, r.a, r.b); return r;
}

__device__ __forceinline__ uint32_t rbits(K2 k, uint32_t p, uint32_t n){
#if PARTITIONABLE
  uint32_t o0, o1; tf2x32(k.a, k.b, 0u, p, o0, o1); return o0 ^ o1;
#else
  uint32_t half = n >> 1;
  uint32_t o0, o1;
  if (p < half){ tf2x32(k.a, k.b, p, p + half, o0, o1); return o0; }
  else         { tf2x32(k.a, k.b, p - half, p, o0, o1); return o1; }
#endif
}

__device__ __forceinline__ float bits2u(uint32_t b){
  return __uint_as_float((b >> 9) | 0x3f800000u) - 1.0f;
}

// ===== Bit-exact XLA-CPU style math (Cephes/Eigen structure, strict f32, no FMA) =====
__device__ __forceinline__ float xla_expf(float x){
#if MATH_XLA_CPU
  #pragma clang fp contract(off)
  const float exp_hi = 88.3762626647950f;
  const float exp_lo = -88.3762626647949f;
  const float log2e  = 1.44269504088896341f;
  const float c1 = 0.693359375f;
  const float c2 = -2.12194440e-4f;
  float xc = fmaxf(fminf(x, exp_hi), exp_lo);
  float fx = floorf(xc * log2e + 0.5f);
  float tmp = fx * c1;
  float z1  = fx * c2;
  float r = xc - tmp;
  r = r - z1;
  float z = r * r;
  float y = 1.9875691500E-4f;
  y = y * r + 1.3981999507E-3f;
  y = y * r + 8.3334519073E-3f;
  y = y * r + 4.1665795894E-2f;
  y = y * r + 1.6666665459E-1f;
  y = y * r + 5.0000001201E-1f;
  y = y * z + r;
  y = y + 1.0f;
  int emm0 = (int)fx + 127;
  float scale = __int_as_float(emm0 << 23);
  return fmaxf(y * scale, x);
#else
  return expf(x);
#endif
}

__device__ __forceinline__ float xla_logf(float a){
#if MATH_XLA_CPU
  #pragma clang fp contract(off)
  float x = fmaxf(a, __uint_as_float(0x00800000u));
  uint32_t bits = __float_as_uint(x);
  int em = (int)(bits >> 23) - 126;
  x = __uint_as_float((bits & 0x007fffffu) | 0x3f000000u);
  float e = (float)em;
  bool mlt = x < 0.707106781186547524f;
  float tmp1 = mlt ? x : 0.0f;
  float xm = x - 1.0f;
  e = e - (mlt ? 1.0f : 0.0f);
  xm = xm + tmp1;
  float z = xm * xm;
  float y = 7.0376836292E-2f;
  y = y * xm + (-1.1514610310E-1f);
  y = y * xm + 1.1676998740E-1f;
  y = y * xm + (-1.2420140846E-1f);
  y = y * xm + 1.4249322787E-1f;
  y = y * xm + (-1.6668057665E-1f);
  y = y * xm + 2.0000714765E-1f;
  y = y * xm + (-2.4999993993E-1f);
  y = y * xm + 3.3333331174E-1f;
  y = y * xm;
  y = y * z;
  y = e * (-2.12194440e-4f) + y;
  y = y - 0.5f * z;
  float res = xm + y;
  res = e * 0.693359375f + res;
  return res;
#else
  return logf(a);
#endif
}

__device__ __forceinline__ float xla_log1pf(float x){
#if MATH_XLA_CPU
  #pragma clang fp contract(off)
  if (fabsf(x) < 1e-4f){
    return ((-0.5f * x) + 1.0f) * x;
  }
  return xla_logf(1.0f + x);
#else
  return log1pf(x);
#endif
}

__device__ __forceinline__ float xla_logaddexp(float a, float b){
  #pragma clang fp contract(off)
  float m = fmaxf(a, b);
  float d = a - b;
  return m + xla_log1pf(xla_expf(-fabsf(d)));
}

template<int NV>
__device__ __forceinline__ float neg_lse_neg(const float* v){
  #pragma clang fp contract(off)
  float m = -v[0];
  #pragma unroll
  for (int i = 1; i < NV; i++) m = fmaxf(m, -v[i]);
  float s = 0.f;
  #pragma unroll
  for (int i = 0; i < NV; i++) s = s + xla_expf((-v[i]) - m);
  return -(xla_logf(s) + m);
}

__device__ __forceinline__ bool bern_bit(float u, float w){
  #pragma clang fp contract(off)
  float e = xla_expf(-w);
  float s = 1.0f / (1.0f + e);
  return u < s;
}

// fast soft-AND for analog-only paths: -logaddexp(-a,-b).
// exact identity: andf(x, 1e30f) == x  (sentinel identity for reductions)
__device__ __forceinline__ float andf(float a, float b){
  float na = -a, nb = -b;
  float m = fmaxf(na, nb);
  float d = fabsf(na - nb);
  return -(m + log1pf(expf(-d)));
}
#define AND_IDENT 1e30f

// ===== Kernel: init (layout detect + s0 codes/scores) =====
__global__ void k_init(const uint32_t* xw, int* flag,
                       const float* s0w, int* s0code, float* s0s){
  __shared__ int any;
  if (threadIdx.x == 0) any = 0;
  __syncthreads();
  int bad = 0;
  for (int i = threadIdx.x; i < 1024; i += 256){
    uint32_t w = xw[i];
    if (w != 0u && w != 1u && w != 0x3F800000u) bad = 1;
  }
  if (bad) atomicOr(&any, 1);
  __syncthreads();
  if (threadIdx.x == 0) *flag = any;   // 1 -> u8 layout, 0 -> 4-byte layout

  int t = threadIdx.x;
  if (t < 32){
    int b = t >> 2, h = t & 3;
    K2 root{0u, 42u};
    K2 sk = kfold(root, 3u);
    float v[NBIT];
    uint32_t code = 0;
    #pragma unroll
    for (int j = 0; j < NBIT; j++){
      float w = s0w[h*NBIT + j];
      uint32_t p = (uint32_t)((b*4 + h)*NBIT + j);
      float u = bits2u(rbits(sk, p, 256u));
      bool bit = bern_bit(u, w);
      code |= (bit ? 1u : 0u) << (NBIT - 1 - j);
      v[j] = bit ? w : -w;
    }
    s0code[t] = (int)code;
    s0s[t]    = neg_lse_neg<NBIT>(v);
  }
}

// ===== Kernel: tree-FFN -> xcode (4-bit) + xss per (b,l,h) row (bit-critical) =====
__global__ __launch_bounds__(256) void k_ffn(const void* xraw, const float* xs,
                                             const float* fk, const float* fv,
                                             uint8_t* xcode, float* xss, const int* flag){
  int r = blockIdx.x * blockDim.x + threadIdx.x;
  if (r >= NROW) return;
  int n = r >> 2;
  int h = r & 3;
  bool u8mode = (*flag != 0);
  const uint8_t* x8   = (const uint8_t*)xraw;
  const uint32_t* x32 = (const uint32_t*)xraw;

  float qs[DD];
  #pragma unroll
  for (int j = 0; j < DD; j++){
    bool qb = u8mode ? (x8[n*DD + j] != 0) : (x32[n*DD + j] != 0u);
    float v = xs[n*DD + j];
    qs[j] = qb ? v : -v;
  }

  K2 root{0u, 42u};
  K2 rngT = kfold(root, 1u);

  uint32_t ix = 0;
  float support = 0.f;
  for (int d = 0; d < DEPTH; d++){
    K2 kd = kfold(rngT, (uint32_t)d);
    const float* kw = fk + (size_t)(h*255 + (1<<d) - 1 + (int)ix) * 16;
    float lor[DD];
    #pragma unroll
    for (int j = 0; j < DD; j++){
      uint32_t p1 = (uint32_t)r * 16u + 2u*(uint32_t)j;
      float u1 = bits2u(rbits(kd, p1,      2097152u));
      float u2 = bits2u(rbits(kd, p1 + 1u, 2097152u));
      float b1 = bern_bit(u1, kw[2*j])     ? 1.f : 0.f;
      float b2 = bern_bit(u2, kw[2*j + 1]) ? 1.f : 0.f;
      float k1 = -xla_logaddexp(-b1,  qs[j]);
      float k2 = -xla_logaddexp(-b2, -qs[j]);
      lor[j] = xla_logaddexp(k1, k2);
    }
    float lor_s = neg_lse_neg<DD>(lor);
    K2 lk = kfold(rngT, 100u + (uint32_t)d);
    float ul = bits2u(rbits(lk, (uint32_t)r, 131072u));
    bool lb = bern_bit(ul, lor_s);
    float ls = lb ? lor_s : -lor_s;
    ix = 2u*ix + (lb ? 1u : 0u);
    support = (d == 0) ? ls : -xla_logaddexp(-support, -ls);
  }

  K2 vk = kfold(rngT, 999u);
  const float* vw = fv + (size_t)(h*256 + (int)ix) * VV;
  float vs[VV];
  uint32_t code = 0;
  #pragma unroll
  for (int c = 0; c < VV; c++){
    float u = bits2u(rbits(vk, (uint32_t)r*4u + (uint32_t)c, 524288u));
    bool b = bern_bit(u, vw[c]);
    code |= (b ? 1u : 0u) << (VV - 1 - c);
    float sv = b ? vw[c] : -vw[c];
    vs[c] = -xla_logaddexp(-sv, -support);
  }
  xcode[r] = (uint8_t)code;
  xss[r]   = neg_lse_neg<VV>(vs);
}

// ===== Kernel: table -> tcode (8-bit next-state) + tabs (bit-critical) =====
__global__ __launch_bounds__(256) void k_table(const float* table, uint8_t* tcode, float* tabs){
  int idx = blockIdx.x * blockDim.x + threadIdx.x;
  if (idx >= 131072) return;
  int rem = idx & 16383;
  K2 root{0u, 42u};
  K2 tk = kfold(root, 2u);
  float v[NBIT];
  uint32_t code = 0;
  #pragma unroll
  for (int j = 0; j < NBIT; j++){
    float w = table[(size_t)rem * NBIT + j];
    uint32_t p = (uint32_t)idx * 8u + (uint32_t)j;
    float u = bits2u(rbits(tk, p, 1048576u));
    bool bit = bern_bit(u, w);
    code |= (bit ? 1u : 0u) << (NBIT - 1 - j);
    v[j] = bit ? w : -w;
  }
  tcode[idx] = (uint8_t)code;
  tabs[idx]  = neg_lse_neg<NBIT>(v);
}

// ===== Phase A: per-chunk all-state map F (states only, no scores) =====
__global__ __launch_bounds__(256) void k_A(const uint8_t* tcode, const uint8_t* xcode,
                                           uint8_t* F){
  int blk = blockIdx.x;          // (b*4+h)*64 + c
  int c  = blk & 63;
  int bh = blk >> 6;
  int b = bh >> 2, h = bh & 3;
  __shared__ int4 sT4[256];      // 4 KB tcode tile
  __shared__ uint8_t sXC[CHUNK];
  uint8_t* sT = (uint8_t*)sT4;
  int t = threadIdx.x;
  const int rowbase = (b*64 + h*16) * 256;
  sT4[t] = ((const int4*)(tcode + rowbase))[t];
  if (t < CHUNK){
    int l = c*CHUNK + t;
    sXC[t] = xcode[(b*LL + l)*HH + h];
  }
  __syncthreads();
  int cur = t;
  #pragma unroll 8
  for (int k = 0; k < CHUNK; k++){
    cur = sT[(int)sXC[k]*256 + cur];
  }
  F[(size_t)blk*256 + t] = (uint8_t)cur;
}

// ===== Phase B: sequential carryZ across chunks, 32 chains =====
__global__ __launch_bounds__(256) void k_B(const uint8_t* F, const int* s0code, int* carryZ){
  int bh = blockIdx.x;           // 0..31
  __shared__ int4 sF4[1024];     // 16 KB
  uint8_t* sF = (uint8_t*)sF4;
  int t = threadIdx.x;
  const int4* src = (const int4*)(F + (size_t)bh*16384);
  for (int i = t; i < 1024; i += 256) sF4[i] = src[i];
  __syncthreads();
  if (t == 0){
    int z = s0code[bh];
    for (int c = 0; c < NCHUNK; c++){ carryZ[bh*NCHUNK + c] = z; z = sF[c*256 + z]; }
  }
}

// ===== Phase C1: chase from carry-in + parallel scores + wave prefix-scan =====
__global__ __launch_bounds__(64) void k_C1(const uint8_t* tcode, const float* tabs,
                                           const uint8_t* xcode, const float* xss,
                                           const int* carryZ,
                                           uint8_t* zOut, float* P, float* T){
  int blk = blockIdx.x;          // (b*4+h)*64 + c
  int c  = blk & 63;
  int bh = blk >> 6;
  int b = bh >> 2, h = bh & 3;
  __shared__ int4 sT4[256];      // 4 KB tcode tile
  uint8_t* sT = (uint8_t*)sT4;
  int t = threadIdx.x;           // 0..63 (one wave)
  const int rowbase = (b*64 + h*16) * 256;
  const int4* src = (const int4*)(tcode + rowbase);
  #pragma unroll
  for (int i = 0; i < 4; i++) sT4[t + 64*i] = src[t + 64*i];

  int l = c*CHUNK + t;
  int r = (b*LL + l)*HH + h;
  int   xcv = xcode[r];
  float xsv = xss[r];
  __syncthreads();

  // redundant all-lane chase (broadcast LDS reads, no divergence)
  int z = carryZ[blk];
  int aReg = 0, zReg = 0;
  for (int k = 0; k < CHUNK; k++){
    int xck = __shfl(xcv, k, 64);
    int a = xck*256 + z;
    z = sT[a];
    if (t == k){ aReg = a; zReg = z; }
  }

  // per-lane score term, then inclusive andf-scan across the wave
  float p = andf(tabs[rowbase + aReg], xsv);
  #pragma unroll
  for (int off = 1; off < 64; off <<= 1){
    float o = __shfl_up(p, off, 64);
    if (t >= off) p = andf(o, p);
  }
  zOut[blk*CHUNK + t] = (uint8_t)zReg;
  P[blk*CHUNK + t] = p;
  if (t == 63) T[blk] = p;       // chunk total (inclusive scan at last lane)
}

// ===== Phase C2: redundant score-carry + coalesced emit =====
__global__ __launch_bounds__(256) void k_C2(const uint8_t* zOut, const float* P,
                                            const float* T, const float* s0s,
                                            float* out){
  int blk = blockIdx.x;          // b*64 + c
  int c = blk & 63;
  int b = blk >> 6;
  __shared__ float carryL[4];
  int t = threadIdx.x;
  int w = t >> 6, lane = t & 63;

  // wave w computes the score carry for head h=w: s0s AND (AND of T over chunks < c)
  float val = (lane < c) ? T[(b*4 + w)*64 + lane] : AND_IDENT;
  #pragma unroll
  for (int off = 1; off < 64; off <<= 1){
    float o = __shfl_xor(val, off, 64);
    val = andf(val, o);
  }
  float carry = andf(val, s0s[b*4 + w]);   // andf(AND_IDENT, x) == x exactly
  if (lane == 0) carryL[w] = carry;
  __syncthreads();

  int k = t >> 2, h = t & 3;
  int cblk = (b*4 + h)*64 + c;
  int z = zOut[cblk*CHUNK + k];
  float sc = andf(carryL[h], P[cblk*CHUNK + k]);

  // out0 offset: ((b*4096 + c*64 + k)*4 + h)*8 + j = blk*2048 + t*8 + j
  size_t base = (size_t)blk*2048 + (size_t)t*8;
  float4 b0, b1;
  b0.x = (float)((z >> 7) & 1); b0.y = (float)((z >> 6) & 1);
  b0.z = (float)((z >> 5) & 1); b0.w = (float)((z >> 4) & 1);
  b1.x = (float)((z >> 3) & 1); b1.y = (float)((z >> 2) & 1);
  b1.z = (float)((z >> 1) & 1); b1.w = (float)( z       & 1);
  float4 s4; s4.x = sc; s4.y = sc; s4.z = sc; s4.w = sc;
  *(float4*)(out + base)     = b0;
  *(float4*)(out + base + 4) = b1;
  *(float4*)(out + 1048576 + base)     = s4;
  *(float4*)(out + 1048576 + base + 4) = s4;
}

extern "C" void kernel_launch(void* const* d_in, const int* in_sizes, int n_in,
                              void* d_out, int out_size, void* d_ws, size_t ws_size,
                              hipStream_t stream) {
  const void*  x      = d_in[0];               // bool (layout detected at runtime)
  const float* xs     = (const float*)d_in[1]; // (8,4096,8)
  const float* fk     = (const float*)d_in[2]; // (4,255,16)
  const float* fv     = (const float*)d_in[3]; // (4,256,4)
  const float* table  = (const float*)d_in[4]; // (1,64,256,8)
  const float* s0w    = (const float*)d_in[5]; // (1,4,8)
  float* out          = (float*)d_out;         // [bits 1048576 | scores 1048576]

  uint8_t* ws = (uint8_t*)d_ws;
  uint8_t* xcode_ = ws;                              // 131072 B
  uint8_t* tcode_ = ws + 131072;                     // 131072 B
  uint8_t* F_     = ws + 262144;                     // 524288 B
  float*   xss_   = (float*)(ws + 786432);           // 524288 B
  float*   tabs_  = (float*)(ws + 1310720);          // 524288 B
  uint8_t* zOut_  = ws + 1835008;                    // 131072 B
  float*   P_     = (float*)(ws + 1966080);          // 524288 B
  float*   T_     = (float*)(ws + 2490368);          // 8192 B
  int*     carryZ_= (int*)  (ws + 2498560);          // 8192 B
  int*     s0code_= (int*)  (ws + 2506752);          // 128 B
  float*   s0s_   = (float*)(ws + 2506880);          // 128 B
  int*     flag_  = (int*)  (ws + 2507008);          // 4 B

  k_init <<<1, 256, 0, stream>>>((const uint32_t*)x, flag_, s0w, s0code_, s0s_);
  k_ffn  <<<NROW/256, 256, 0, stream>>>(x, xs, fk, fv, xcode_, xss_, flag_);
  k_table<<<131072/256, 256, 0, stream>>>(table, tcode_, tabs_);
  k_A    <<<32*NCHUNK, 256, 0, stream>>>(tcode_, xcode_, F_);
  k_B    <<<32, 256, 0, stream>>>(F_, s0code_, carryZ_);
  k_C1   <<<32*NCHUNK, 64, 0, stream>>>(tcode_, tabs_, xcode_, xss_, carryZ_, zOut_, P_, T_);
  k_C2   <<<BB*NCHUNK, 256, 0, stream>>>(zOut_, P_, T_, s0s_, out);
}